// Round 2
// baseline (20007.674 us; speedup 1.0000x reference)
//
#include <hip/hip_runtime.h>
#include <stdint.h>

typedef unsigned short ushort_t;

#define B_ 4
#define H_ 256
#define W_ 256
#define C_ 128
#define WS_ 8
#define SS_ 4
#define NH_ 4
#define HD_ 32
#define NT_ 64
#define EPSV 1.001e-05f
#define QSCALE 0.17677669529663687f

__device__ __forceinline__ float bf2f(ushort_t u) {
  return __uint_as_float(((unsigned int)u) << 16);
}
__device__ __forceinline__ ushort_t f2bf(float f) {
  unsigned int u = __float_as_uint(f);
  u += 0x7fffu + ((u >> 16) & 1u);   // round-nearest-even
  return (ushort_t)(u >> 16);
}
__device__ __forceinline__ void ld8f(const float* p, float* f) {
  float4 a = *reinterpret_cast<const float4*>(p);
  float4 b = *reinterpret_cast<const float4*>(p + 4);
  f[0]=a.x; f[1]=a.y; f[2]=a.z; f[3]=a.w;
  f[4]=b.x; f[5]=b.y; f[6]=b.z; f[7]=b.w;
}
__device__ __forceinline__ float wred_sum(float v) {
  v += __shfl_xor(v, 1);  v += __shfl_xor(v, 2);  v += __shfl_xor(v, 4);
  v += __shfl_xor(v, 8);  v += __shfl_xor(v, 16); v += __shfl_xor(v, 32);
  return v;
}

// ---------------- Kernel A: LN1 + shifted-window attention + proj + residual ----------------
template <typename YT>
__global__ __launch_bounds__(256)
void swin_attn_k(const float* __restrict__ x,
                 const float* __restrict__ g1, const float* __restrict__ be1,
                 const float* __restrict__ qkvw, const float* __restrict__ qkvb,
                 const float* __restrict__ projw, const float* __restrict__ projb,
                 const float* __restrict__ rpb,
                 YT* __restrict__ y)
{
  // LDS layout (byte offsets):
  //  [0,16896)      xw  bf16[64][132]
  //  [16896,25344)  qs  f32[64][33]
  //  [25344,33792)  ks  f32[64][33]
  //  [33792,42240)  vs  f32[64][33]
  //  [0,33280)      yst f32[64][130]   (aliases xw/qs/part-of-ks after head loop)
  //  [42240,59136)  ob  bf16[64][132]
  __shared__ __align__(16) char smem[59136];
  ushort_t (*xw)[132]  = reinterpret_cast<ushort_t(*)[132]>(smem);
  float    (*qs)[33]   = reinterpret_cast<float(*)[33]>(smem + 16896);
  float    (*ks)[33]   = reinterpret_cast<float(*)[33]>(smem + 25344);
  float    (*vs)[33]   = reinterpret_cast<float(*)[33]>(smem + 33792);
  float    (*yst)[130] = reinterpret_cast<float(*)[130]>(smem);
  ushort_t (*ob)[132]  = reinterpret_cast<ushort_t(*)[132]>(smem + 42240);
  __shared__ int rowoff[NT_];
  __shared__ int lab[NT_];

  const int tid  = threadIdx.x;
  const int lane = tid & 63;
  const int wave = tid >> 6;
  const int blk  = blockIdx.x;
  const int b    = blk >> 10;
  const int w    = blk & 1023;
  const int wh   = w >> 5, ww = w & 31;

  if (tid < NT_) {
    int th = tid >> 3, tw = tid & 7;
    int shh = wh * WS_ + th, shw = ww * WS_ + tw;         // shifted-frame coords
    int oh = (shh + SS_) & (H_ - 1);                       // original coords (roll -SS)
    int ow = (shw + SS_) & (W_ - 1);
    rowoff[tid] = ((b * H_ + oh) * W_ + ow) * C_;
    int hb = (shh < H_ - WS_) ? 0 : ((shh < H_ - SS_) ? 1 : 2);
    int wb = (shw < W_ - WS_) ? 0 : ((shw < W_ - SS_) ? 1 : 2);
    lab[tid] = hb * 3 + wb;
  }
  __syncthreads();

  // LN1 -> xw (wave per token, 2 channels per lane)
  {
    float gv0 = g1[2*lane],  gv1 = g1[2*lane+1];
    float bv0 = be1[2*lane], bv1 = be1[2*lane+1];
    for (int i = wave*16; i < wave*16 + 16; ++i) {
      float2 rv = *reinterpret_cast<const float2*>(x + rowoff[i] + 2*lane);
      float x0 = rv.x, x1 = rv.y;
      float s  = wred_sum(x0 + x1);
      float s2 = wred_sum(x0*x0 + x1*x1);
      float mean = s * (1.0f/128.0f);
      float var  = s2 * (1.0f/128.0f) - mean*mean;
      float rs = rsqrtf(var + EPSV);
      xw[i][2*lane]   = f2bf((x0 - mean) * rs * gv0 + bv0);
      xw[i][2*lane+1] = f2bf((x1 - mean) * rs * gv1 + bv1);
    }
  }
  __syncthreads();

  const int i2 = tid >> 2;        // token row this thread owns
  const int cs = tid & 3;         // 4-lane sub-group id
  const int ih = i2 >> 3, iw = i2 & 7;
  const int myLab = lab[i2];

  for (int h = 0; h < NH_; ++h) {
    // ---- QKV (this head): thread computes 8 consecutive cols of q,k,v for row i2 ----
    {
      float accq[8], acck[8], accv[8];
      {
        const float* bq = qkvb + h*HD_ + cs*8;
        const float* bk = qkvb + C_   + h*HD_ + cs*8;
        const float* bv = qkvb + 2*C_ + h*HD_ + cs*8;
        #pragma unroll
        for (int jj = 0; jj < 8; ++jj) {
          accq[jj] = bq[jj]; acck[jj] = bk[jj]; accv[jj] = bv[jj];
        }
      }
      for (int kk = 0; kk < C_; ++kk) {
        float xv = bf2f(xw[i2][kk]);
        const float* wr = qkvw + kk*(3*C_) + h*HD_ + cs*8;
        float wf[8];
        ld8f(wr, wf);
        #pragma unroll
        for (int jj = 0; jj < 8; ++jj) accq[jj] += xv*wf[jj];
        ld8f(wr + C_, wf);
        #pragma unroll
        for (int jj = 0; jj < 8; ++jj) acck[jj] += xv*wf[jj];
        ld8f(wr + 2*C_, wf);
        #pragma unroll
        for (int jj = 0; jj < 8; ++jj) accv[jj] += xv*wf[jj];
      }
      #pragma unroll
      for (int jj = 0; jj < 8; ++jj) {
        qs[i2][cs*8+jj] = accq[jj]*QSCALE;
        ks[i2][cs*8+jj] = acck[jj];
        vs[i2][cs*8+jj] = accv[jj];
      }
    }
    __syncthreads();

    // ---- scores (+bias,+mask) + softmax + PV ----
    {
      float qreg[HD_];
      #pragma unroll
      for (int d = 0; d < HD_; ++d) qreg[d] = qs[i2][d];
      float p[16];
      float mx = -1e30f;
      for (int jj = 0; jj < 16; ++jj) {
        int j = cs*16 + jj;
        float s = 0.f;
        #pragma unroll
        for (int d = 0; d < HD_; ++d) s += qreg[d]*ks[j][d];
        int jh = j >> 3, jw = j & 7;
        int rel = (ih - jh + 7)*15 + (iw - jw + 7);
        s += rpb[rel*4 + h];
        s += (lab[j] != myLab) ? -100.f : 0.f;
        p[jj] = s;
        mx = fmaxf(mx, s);
      }
      mx = fmaxf(mx, __shfl_xor(mx, 1));
      mx = fmaxf(mx, __shfl_xor(mx, 2));
      float sum = 0.f;
      #pragma unroll
      for (int jj = 0; jj < 16; ++jj) { p[jj] = __expf(p[jj]-mx); sum += p[jj]; }
      sum += __shfl_xor(sum, 1);
      sum += __shfl_xor(sum, 2);
      float rinv = 1.0f / sum;
      float po[HD_];
      #pragma unroll
      for (int d = 0; d < HD_; ++d) po[d] = 0.f;
      for (int jj = 0; jj < 16; ++jj) {
        int j = cs*16 + jj;
        float pv = p[jj]*rinv;
        #pragma unroll
        for (int d = 0; d < HD_; ++d) po[d] += pv*vs[j][d];
      }
      #pragma unroll
      for (int d = 0; d < HD_; ++d) {
        po[d] += __shfl_xor(po[d], 1);
        po[d] += __shfl_xor(po[d], 2);
      }
      #pragma unroll
      for (int dd = 0; dd < 8; ++dd)
        ob[i2][h*HD_ + cs*8 + dd] = f2bf(po[cs*8 + dd]);
    }
    __syncthreads();
  }

  // ---- proj -> yst (aliases dead xw/q/k regions) ----
  {
    float acc[32];
    const float* pb = projb + cs*32;
    #pragma unroll
    for (int c = 0; c < 32; ++c) acc[c] = pb[c];
    for (int kk = 0; kk < C_; ++kk) {
      float ov = bf2f(ob[i2][kk]);
      const float* wr = projw + kk*C_ + cs*32;
      float wf[8];
      #pragma unroll
      for (int seg = 0; seg < 4; ++seg) {
        ld8f(wr + seg*8, wf);
        #pragma unroll
        for (int jj = 0; jj < 8; ++jj) acc[seg*8+jj] += ov*wf[jj];
      }
    }
    #pragma unroll
    for (int c = 0; c < 32; ++c) yst[i2][cs*32+c] = acc[c];
  }
  __syncthreads();

  // ---- y = x + attn_out, coalesced via staging ----
  for (int i = wave*16; i < wave*16 + 16; ++i) {
    int ro = rowoff[i];
    float2 pr = *reinterpret_cast<float2*>(&yst[i][2*lane]);
    float2 rv = *reinterpret_cast<const float2*>(x + ro + 2*lane);
    float y0 = pr.x + rv.x;
    float y1 = pr.y + rv.y;
    if constexpr (sizeof(YT) == 4) {
      *reinterpret_cast<float2*>(reinterpret_cast<float*>(y) + ro + 2*lane) = make_float2(y0, y1);
    } else {
      ushort2 o2; o2.x = f2bf(y0); o2.y = f2bf(y1);
      *reinterpret_cast<ushort2*>(reinterpret_cast<ushort_t*>(y) + ro + 2*lane) = o2;
    }
  }
}

// ---------------- Kernel B: LN2 + MLP + residual ----------------
template <typename YT>
__global__ __launch_bounds__(256)
void swin_mlp_k(const YT* __restrict__ y,
                const float* __restrict__ g2, const float* __restrict__ be2,
                const float* __restrict__ w1, const float* __restrict__ b1,
                const float* __restrict__ w2, const float* __restrict__ b2,
                float* __restrict__ out)
{
  __shared__ ushort_t hsm[NT_][132];   // LN2 output, bf16
  __shared__ float    asm2[NT_][130];  // gelu(h@w1) chunk / out staging
  const int tid = threadIdx.x, lane = tid & 63, wave = tid >> 6;
  const long tb = (long)blockIdx.x * NT_;

  {
    float gv0 = g2[2*lane],  gv1 = g2[2*lane+1];
    float bv0 = be2[2*lane], bv1 = be2[2*lane+1];
    for (int i = wave*16; i < wave*16 + 16; ++i) {
      size_t base = (size_t)(tb + i)*C_ + 2*lane;
      float x0, x1;
      if constexpr (sizeof(YT) == 4) {
        float2 rv = *reinterpret_cast<const float2*>(reinterpret_cast<const float*>(y) + base);
        x0 = rv.x; x1 = rv.y;
      } else {
        ushort2 rv = *reinterpret_cast<const ushort2*>(reinterpret_cast<const ushort_t*>(y) + base);
        x0 = bf2f(rv.x); x1 = bf2f(rv.y);
      }
      float s  = wred_sum(x0 + x1);
      float s2 = wred_sum(x0*x0 + x1*x1);
      float mean = s * (1.0f/128.0f);
      float var  = s2 * (1.0f/128.0f) - mean*mean;
      float rs = rsqrtf(var + EPSV);
      hsm[i][2*lane]   = f2bf((x0 - mean)*rs*gv0 + bv0);
      hsm[i][2*lane+1] = f2bf((x1 - mean)*rs*gv1 + bv1);
    }
  }
  __syncthreads();

  const int i2 = tid >> 2, cs = tid & 3;
  float acc[32];
  {
    const float* bp = b2 + cs*32;
    #pragma unroll
    for (int c = 0; c < 32; ++c) acc[c] = bp[c];
  }

  for (int jc = 0; jc < 4; ++jc) {
    // a-chunk: 128 hidden cols
    float aacc[32];
    {
      const float* bp = b1 + jc*128 + cs*32;
      #pragma unroll
      for (int c = 0; c < 32; ++c) aacc[c] = bp[c];
    }
    for (int kk = 0; kk < C_; ++kk) {
      float hv = bf2f(hsm[i2][kk]);
      const float* wr = w1 + kk*512 + jc*128 + cs*32;
      float wf[8];
      #pragma unroll
      for (int seg = 0; seg < 4; ++seg) {
        ld8f(wr + seg*8, wf);
        #pragma unroll
        for (int jj = 0; jj < 8; ++jj) aacc[seg*8+jj] += hv*wf[jj];
      }
    }
    __syncthreads();   // previous chunk's asm2 readers are done
    #pragma unroll
    for (int c = 0; c < 32; ++c) {
      float vv = aacc[c];
      asm2[i2][cs*32+c] = 0.5f*vv*(1.0f + erff(vv*0.70710678118654752f));
    }
    __syncthreads();
    for (int jj = 0; jj < C_; ++jj) {
      float av = asm2[i2][jj];
      const float* wr = w2 + (jc*128 + jj)*C_ + cs*32;
      float wf[8];
      #pragma unroll
      for (int seg = 0; seg < 4; ++seg) {
        ld8f(wr + seg*8, wf);
        #pragma unroll
        for (int c = 0; c < 8; ++c) acc[seg*8+c] += av*wf[c];
      }
    }
  }
  __syncthreads();
  #pragma unroll
  for (int c = 0; c < 32; ++c) asm2[i2][cs*32+c] = acc[c];
  __syncthreads();

  for (int i = wave*16; i < wave*16 + 16; ++i) {
    size_t base = (size_t)(tb + i)*C_ + 2*lane;
    float2 pr = *reinterpret_cast<float2*>(&asm2[i][2*lane]);
    float x0, x1;
    if constexpr (sizeof(YT) == 4) {
      float2 rv = *reinterpret_cast<const float2*>(reinterpret_cast<const float*>(y) + base);
      x0 = rv.x; x1 = rv.y;
    } else {
      ushort2 rv = *reinterpret_cast<const ushort2*>(reinterpret_cast<const ushort_t*>(y) + base);
      x0 = bf2f(rv.x); x1 = bf2f(rv.y);
    }
    *reinterpret_cast<float2*>(out + base) = make_float2(x0 + pr.x, x1 + pr.y);
  }
}

extern "C" void kernel_launch(void* const* d_in, const int* in_sizes, int n_in,
                              void* d_out, int out_size, void* d_ws, size_t ws_size,
                              hipStream_t stream) {
  const float* x    = (const float*)d_in[0];
  const float* g1   = (const float*)d_in[1];
  const float* be1  = (const float*)d_in[2];
  const float* qkvw = (const float*)d_in[3];
  const float* qkvb = (const float*)d_in[4];
  const float* pw   = (const float*)d_in[5];
  const float* pb   = (const float*)d_in[6];
  const float* rpb  = (const float*)d_in[7];
  const float* g2   = (const float*)d_in[8];
  const float* be2  = (const float*)d_in[9];
  const float* w1   = (const float*)d_in[10];
  const float* b1   = (const float*)d_in[11];
  const float* w2   = (const float*)d_in[12];
  const float* b2   = (const float*)d_in[13];
  float* out = (float*)d_out;

  const size_t nElem = (size_t)B_ * H_ * W_ * C_;
  dim3 grid(4096), blk(256);

  if (ws_size >= nElem * sizeof(float)) {
    float* yv = (float*)d_ws;
    swin_attn_k<float><<<grid, blk, 0, stream>>>(x, g1, be1, qkvw, qkvb, pw, pb, rpb, yv);
    swin_mlp_k<float><<<grid, blk, 0, stream>>>(yv, g2, be2, w1, b1, w2, b2, out);
  } else {
    ushort_t* yv = (ushort_t*)d_ws;
    swin_attn_k<ushort_t><<<grid, blk, 0, stream>>>(x, g1, be1, qkvw, qkvb, pw, pb, rpb, yv);
    swin_mlp_k<ushort_t><<<grid, blk, 0, stream>>>(yv, g2, be2, w1, b1, w2, b2, out);
  }
}

// Round 3
// 613.044 us; speedup vs baseline: 32.6366x; 32.6366x over previous
//
#include <hip/hip_runtime.h>
#include <stdint.h>

typedef unsigned short ushort_t;
typedef __bf16 bf16_t;
typedef bf16_t bf16x8 __attribute__((ext_vector_type(8)));
typedef float f32x4 __attribute__((ext_vector_type(4)));

#define H_ 256
#define W_ 256
#define C_ 128
#define WS_ 8
#define SS_ 4
#define NT_ 64
#define EPSV 1.001e-05f
#define QSCALE 0.17677669529663687f

// d_ws layout (bytes)
#define WSO_QKVW 0u         // ushort[24*4*512]  = 98304 B
#define WSO_PROJW 98304u    // ushort[8*4*512]   = 32768 B
#define WSO_W1   131072u    // ushort[32*4*512]  = 131072 B
#define WSO_W2   262144u    // ushort[8*16*512]  = 131072 B
#define WSO_BIAS 393216u    // float[4*64*64]    = 65536 B
#define WSO_Y    524288u

__device__ __forceinline__ ushort_t f2bf(float f) {
  unsigned int u = __float_as_uint(f);
  u += 0x7fffu + ((u >> 16) & 1u);   // RNE
  return (ushort_t)(u >> 16);
}
__device__ __forceinline__ float bf2f(ushort_t u) {
  return __uint_as_float(((unsigned int)u) << 16);
}
__device__ __forceinline__ float wred_sum(float v) {
  v += __shfl_xor(v, 1);  v += __shfl_xor(v, 2);  v += __shfl_xor(v, 4);
  v += __shfl_xor(v, 8);  v += __shfl_xor(v, 16); v += __shfl_xor(v, 32);
  return v;
}
// bf16 LDS tile access, XOR-swizzled (row stride rowB bytes, multiple of 128)
__device__ __forceinline__ bf16x8 ldfrag(const char* base, int rowB, int row, int col) {
  int off = row * rowB + ((col * 2) ^ ((row & 7) << 4));
  return *reinterpret_cast<const bf16x8*>(base + off);
}
__device__ __forceinline__ void stbf(char* base, int rowB, int row, int col, float v) {
  int off = row * rowB + ((col * 2) ^ ((row & 7) << 4));
  *reinterpret_cast<ushort_t*>(base + off) = f2bf(v);
}
__device__ __forceinline__ float gelu_f(float v) {
  return 0.5f * v * (1.0f + erff(v * 0.70710678118654752f));
}

// ---------------- prep: weights -> bf16 fragment-major, bias table ----------------
__global__ __launch_bounds__(256)
void prep_k(const float* __restrict__ qkvw, const float* __restrict__ projw,
            const float* __restrict__ w1, const float* __restrict__ w2,
            const float* __restrict__ rpb, char* __restrict__ ws)
{
  int idx = blockIdx.x * 256 + threadIdx.x;   // grid 832 -> 212992 exact
  if (idx < 49152) {                          // qkvw frags: 24 ntiles x 4 ks
    int t = idx >> 9, r = idx & 511; int l = r >> 3, j = r & 7;
    int gn = t >> 2, ks = t & 3;
    int k = ks*32 + (l>>4)*8 + j, n = gn*16 + (l&15);
    ((ushort_t*)(ws + WSO_QKVW))[idx] = f2bf(qkvw[k*384 + n]);
  } else if (idx < 65536) {                   // projw: 8 x 4
    int i = idx - 49152;
    int t = i >> 9, r = i & 511; int l = r >> 3, j = r & 7;
    int gn = t >> 2, ks = t & 3;
    int k = ks*32 + (l>>4)*8 + j, n = gn*16 + (l&15);
    ((ushort_t*)(ws + WSO_PROJW))[i] = f2bf(projw[k*128 + n]);
  } else if (idx < 131072) {                  // w1: 32 x 4
    int i = idx - 65536;
    int t = i >> 9, r = i & 511; int l = r >> 3, j = r & 7;
    int gn = t >> 2, ks = t & 3;
    int k = ks*32 + (l>>4)*8 + j, n = gn*16 + (l&15);
    ((ushort_t*)(ws + WSO_W1))[i] = f2bf(w1[k*512 + n]);
  } else if (idx < 196608) {                  // w2: 8 ntiles x 16 ks
    int i = idx - 131072;
    int t = i >> 9, r = i & 511; int l = r >> 3, j = r & 7;
    int gn = t >> 4, ks = t & 15;
    int k = ks*32 + (l>>4)*8 + j, n = gn*16 + (l&15);
    ((ushort_t*)(ws + WSO_W2))[i] = f2bf(w2[k*128 + n]);
  } else {                                    // bias table [4][64][64]
    int i = idx - 196608;
    int h = i >> 12, ij = i & 4095, ti = ij >> 6, tj = ij & 63;
    int rel = ((ti>>3) - (tj>>3) + 7)*15 + ((ti&7) - (tj&7) + 7);
    ((float*)(ws + WSO_BIAS))[i] = rpb[rel*4 + h];
  }
}

// ---------------- Kernel A: LN1 + window attention (MFMA) + proj + residual ----------------
template <typename YT>
__global__ __launch_bounds__(256)
void swin_attn_k(const float* __restrict__ x,
                 const float* __restrict__ g1, const float* __restrict__ be1,
                 const float* __restrict__ qkvb, const float* __restrict__ projb,
                 const char* __restrict__ ws, YT* __restrict__ y)
{
  // regions: [0,16384) xw -> ob ; [16384,49152) q,k -> P(4x8192) ; [49152,65536) vT
  __shared__ __align__(16) char smem[65536];
  __shared__ int rowoff[NT_];
  __shared__ int lab[NT_];
  char* xw = smem;
  char* qr = smem + 16384;
  char* kr = smem + 32768;
  char* vT = smem + 49152;

  const ushort_t* qkvw_f  = (const ushort_t*)(ws + WSO_QKVW);
  const ushort_t* projw_f = (const ushort_t*)(ws + WSO_PROJW);
  const float*    biasT   = (const float*)(ws + WSO_BIAS);

  const int tid = threadIdx.x, lane = tid & 63, wave = tid >> 6;
  const int l15 = lane & 15, lg = lane >> 4;
  const int blk = blockIdx.x;
  const int b = blk >> 10, w = blk & 1023;
  const int wh = w >> 5, ww = w & 31;

  if (tid < NT_) {
    int th = tid >> 3, tw = tid & 7;
    int shh = wh*WS_ + th, shw = ww*WS_ + tw;
    int oh = (shh + SS_) & (H_-1), ow = (shw + SS_) & (W_-1);
    rowoff[tid] = ((b*H_ + oh)*W_ + ow) * C_;
    int hb = (shh < H_-WS_) ? 0 : ((shh < H_-SS_) ? 1 : 2);
    int wb = (shw < W_-WS_) ? 0 : ((shw < W_-SS_) ? 1 : 2);
    lab[tid] = hb*3 + wb;
  }
  __syncthreads();

  { // LN1 -> xw (swizzled bf16)
    float gv0 = g1[2*lane], gv1 = g1[2*lane+1];
    float bv0 = be1[2*lane], bv1 = be1[2*lane+1];
    for (int i = wave*16; i < wave*16 + 16; ++i) {
      float2 rv = *reinterpret_cast<const float2*>(x + rowoff[i] + 2*lane);
      float s  = wred_sum(rv.x + rv.y);
      float s2 = wred_sum(rv.x*rv.x + rv.y*rv.y);
      float mean = s*(1.f/128.f), var = s2*(1.f/128.f) - mean*mean;
      float rs = rsqrtf(var + EPSV);
      unsigned int pk = (unsigned)f2bf((rv.x-mean)*rs*gv0 + bv0)
                      | ((unsigned)f2bf((rv.y-mean)*rs*gv1 + bv1) << 16);
      int off = i*256 + ((lane*4) ^ ((i&7) << 4));
      *reinterpret_cast<unsigned int*>(xw + off) = pk;
    }
  }
  __syncthreads();

  { // QKV GEMM: 6 n-tiles per wave
    bf16x8 afr[4][4];
    #pragma unroll
    for (int mi = 0; mi < 4; ++mi)
      #pragma unroll
      for (int ks = 0; ks < 4; ++ks)
        afr[mi][ks] = ldfrag(xw, 256, l15 + mi*16, ks*32 + lg*8);
    for (int nt = 0; nt < 6; ++nt) {
      int gn = wave*6 + nt;
      f32x4 acc[4] = {{0,0,0,0},{0,0,0,0},{0,0,0,0},{0,0,0,0}};
      #pragma unroll
      for (int ks = 0; ks < 4; ++ks) {
        bf16x8 bf = *reinterpret_cast<const bf16x8*>(qkvw_f + (size_t)(gn*4 + ks)*512 + lane*8);
        #pragma unroll
        for (int mi = 0; mi < 4; ++mi)
          acc[mi] = __builtin_amdgcn_mfma_f32_16x16x32_bf16(afr[mi][ks], bf, acc[mi], 0, 0, 0);
      }
      float bv = qkvb[gn*16 + l15];
      if (gn < 8) {
        #pragma unroll
        for (int mi = 0; mi < 4; ++mi)
          #pragma unroll
          for (int rr = 0; rr < 4; ++rr)
            stbf(qr, 256, mi*16 + lg*4 + rr, gn*16 + l15, (acc[mi][rr] + bv)*QSCALE);
      } else if (gn < 16) {
        #pragma unroll
        for (int mi = 0; mi < 4; ++mi)
          #pragma unroll
          for (int rr = 0; rr < 4; ++rr)
            stbf(kr, 256, mi*16 + lg*4 + rr, (gn-8)*16 + l15, acc[mi][rr] + bv);
      } else {
        #pragma unroll
        for (int mi = 0; mi < 4; ++mi)
          #pragma unroll
          for (int rr = 0; rr < 4; ++rr)
            stbf(vT, 128, (gn-16)*16 + l15, mi*16 + lg*4 + rr, acc[mi][rr] + bv);
      }
    }
  }
  __syncthreads();

  float rinv[4][4];
  { // per-head attention, head = wave
    const int h = wave;
    bf16x8 qa[4], kb[4];
    #pragma unroll
    for (int mi = 0; mi < 4; ++mi) qa[mi] = ldfrag(qr, 256, l15 + mi*16, h*32 + lg*8);
    #pragma unroll
    for (int ni = 0; ni < 4; ++ni) kb[ni] = ldfrag(kr, 256, l15 + ni*16, h*32 + lg*8);
    f32x4 S[4][4];
    #pragma unroll
    for (int mi = 0; mi < 4; ++mi)
      #pragma unroll
      for (int ni = 0; ni < 4; ++ni) {
        f32x4 z = {0,0,0,0};
        S[mi][ni] = __builtin_amdgcn_mfma_f32_16x16x32_bf16(qa[mi], kb[ni], z, 0, 0, 0);
      }
    int labC[4];
    #pragma unroll
    for (int ni = 0; ni < 4; ++ni) labC[ni] = lab[ni*16 + l15];
    #pragma unroll
    for (int mi = 0; mi < 4; ++mi)
      #pragma unroll
      for (int rr = 0; rr < 4; ++rr) {
        int row = mi*16 + lg*4 + rr;
        int labR = lab[row];
        const float* bp = biasT + h*4096 + row*64 + l15;
        #pragma unroll
        for (int ni = 0; ni < 4; ++ni)
          S[mi][ni][rr] += bp[ni*16] + ((labC[ni] == labR) ? 0.f : -100.f);
      }
    // softmax (rows live on 16-lane groups)
    #pragma unroll
    for (int mi = 0; mi < 4; ++mi)
      #pragma unroll
      for (int rr = 0; rr < 4; ++rr) {
        float mx = fmaxf(fmaxf(S[mi][0][rr], S[mi][1][rr]), fmaxf(S[mi][2][rr], S[mi][3][rr]));
        mx = fmaxf(mx, __shfl_xor(mx, 1)); mx = fmaxf(mx, __shfl_xor(mx, 2));
        mx = fmaxf(mx, __shfl_xor(mx, 4)); mx = fmaxf(mx, __shfl_xor(mx, 8));
        float sum = 0.f;
        #pragma unroll
        for (int ni = 0; ni < 4; ++ni) {
          float e = __expf(S[mi][ni][rr] - mx);
          S[mi][ni][rr] = e; sum += e;
        }
        sum += __shfl_xor(sum, 1); sum += __shfl_xor(sum, 2);
        sum += __shfl_xor(sum, 4); sum += __shfl_xor(sum, 8);
        rinv[mi][rr] = 1.0f / sum;
      }
    __syncthreads();   // all waves done reading q/k -> P may overwrite that region
    char* Pw = smem + 16384 + wave*8192;   // per-wave [64][64] bf16 swz
    #pragma unroll
    for (int mi = 0; mi < 4; ++mi)
      #pragma unroll
      for (int ni = 0; ni < 4; ++ni)
        #pragma unroll
        for (int rr = 0; rr < 4; ++rr)
          stbf(Pw, 128, mi*16 + lg*4 + rr, ni*16 + l15, S[mi][ni][rr]);
    // PV
    f32x4 O[4][2] = {{{0,0,0,0},{0,0,0,0}},{{0,0,0,0},{0,0,0,0}},
                     {{0,0,0,0},{0,0,0,0}},{{0,0,0,0},{0,0,0,0}}};
    #pragma unroll
    for (int ks = 0; ks < 2; ++ks) {
      bf16x8 pa[4];
      #pragma unroll
      for (int mi = 0; mi < 4; ++mi) pa[mi] = ldfrag(Pw, 128, l15 + mi*16, ks*32 + lg*8);
      #pragma unroll
      for (int ni = 0; ni < 2; ++ni) {
        bf16x8 vb = ldfrag(vT, 128, h*32 + ni*16 + l15, ks*32 + lg*8);
        #pragma unroll
        for (int mi = 0; mi < 4; ++mi)
          O[mi][ni] = __builtin_amdgcn_mfma_f32_16x16x32_bf16(pa[mi], vb, O[mi][ni], 0, 0, 0);
      }
    }
    // normalized O -> ob (aliases xw)
    #pragma unroll
    for (int mi = 0; mi < 4; ++mi)
      #pragma unroll
      for (int ni = 0; ni < 2; ++ni)
        #pragma unroll
        for (int rr = 0; rr < 4; ++rr)
          stbf(xw, 256, mi*16 + lg*4 + rr, h*32 + ni*16 + l15, O[mi][ni][rr]*rinv[mi][rr]);
  }
  __syncthreads();

  { // proj + residual + store y
    bf16x8 oa[4][4];
    #pragma unroll
    for (int mi = 0; mi < 4; ++mi)
      #pragma unroll
      for (int ks = 0; ks < 4; ++ks)
        oa[mi][ks] = ldfrag(xw, 256, l15 + mi*16, ks*32 + lg*8);
    #pragma unroll
    for (int g = 0; g < 2; ++g) {
      int gn = wave*2 + g;
      f32x4 acc[4] = {{0,0,0,0},{0,0,0,0},{0,0,0,0},{0,0,0,0}};
      #pragma unroll
      for (int ks = 0; ks < 4; ++ks) {
        bf16x8 bf = *reinterpret_cast<const bf16x8*>(projw_f + (size_t)(gn*4 + ks)*512 + lane*8);
        #pragma unroll
        for (int mi = 0; mi < 4; ++mi)
          acc[mi] = __builtin_amdgcn_mfma_f32_16x16x32_bf16(oa[mi][ks], bf, acc[mi], 0, 0, 0);
      }
      float pbv = projb[gn*16 + l15];
      #pragma unroll
      for (int mi = 0; mi < 4; ++mi)
        #pragma unroll
        for (int rr = 0; rr < 4; ++rr) {
          int tok = mi*16 + lg*4 + rr;
          int ro = rowoff[tok] + gn*16 + l15;
          float v = acc[mi][rr] + pbv + x[ro];
          if constexpr (sizeof(YT) == 4) ((float*)y)[ro] = v;
          else ((ushort_t*)y)[ro] = f2bf(v);
        }
    }
  }
}

// ---------------- Kernel B: LN2 + MLP (MFMA) + residual ----------------
template <typename YT>
__global__ __launch_bounds__(256)
void swin_mlp_k(const YT* __restrict__ y,
                const float* __restrict__ g2, const float* __restrict__ be2,
                const float* __restrict__ b1, const float* __restrict__ b2,
                const char* __restrict__ ws, float* __restrict__ out)
{
  __shared__ __align__(16) char smem[81920];   // hsm [0,16384) ; a [16384,81920)
  char* hsm = smem;
  char* ar  = smem + 16384;
  const ushort_t* w1_f = (const ushort_t*)(ws + WSO_W1);
  const ushort_t* w2_f = (const ushort_t*)(ws + WSO_W2);

  const int tid = threadIdx.x, lane = tid & 63, wave = tid >> 6;
  const int l15 = lane & 15, lg = lane >> 4;
  const long tb = (long)blockIdx.x * NT_;

  { // LN2 -> hsm
    float gv0 = g2[2*lane], gv1 = g2[2*lane+1];
    float bv0 = be2[2*lane], bv1 = be2[2*lane+1];
    for (int i = wave*16; i < wave*16 + 16; ++i) {
      size_t base = (size_t)(tb + i)*C_ + 2*lane;
      float x0, x1;
      if constexpr (sizeof(YT) == 4) {
        float2 rv = *reinterpret_cast<const float2*>((const float*)y + base);
        x0 = rv.x; x1 = rv.y;
      } else {
        ushort2 rv = *reinterpret_cast<const ushort2*>((const ushort_t*)y + base);
        x0 = bf2f(rv.x); x1 = bf2f(rv.y);
      }
      float s  = wred_sum(x0 + x1);
      float s2 = wred_sum(x0*x0 + x1*x1);
      float mean = s*(1.f/128.f), var = s2*(1.f/128.f) - mean*mean;
      float rs = rsqrtf(var + EPSV);
      unsigned int pk = (unsigned)f2bf((x0-mean)*rs*gv0 + bv0)
                      | ((unsigned)f2bf((x1-mean)*rs*gv1 + bv1) << 16);
      int off = i*256 + ((lane*4) ^ ((i&7) << 4));
      *reinterpret_cast<unsigned int*>(hsm + off) = pk;
    }
  }
  __syncthreads();

  { // GEMM1 + GELU -> a
    bf16x8 ha[4][4];
    #pragma unroll
    for (int mi = 0; mi < 4; ++mi)
      #pragma unroll
      for (int ks = 0; ks < 4; ++ks)
        ha[mi][ks] = ldfrag(hsm, 256, l15 + mi*16, ks*32 + lg*8);
    for (int g = 0; g < 8; ++g) {
      int gn = wave*8 + g;
      f32x4 acc[4] = {{0,0,0,0},{0,0,0,0},{0,0,0,0},{0,0,0,0}};
      #pragma unroll
      for (int ks = 0; ks < 4; ++ks) {
        bf16x8 bf = *reinterpret_cast<const bf16x8*>(w1_f + (size_t)(gn*4 + ks)*512 + lane*8);
        #pragma unroll
        for (int mi = 0; mi < 4; ++mi)
          acc[mi] = __builtin_amdgcn_mfma_f32_16x16x32_bf16(ha[mi][ks], bf, acc[mi], 0, 0, 0);
      }
      float b1v = b1[gn*16 + l15];
      #pragma unroll
      for (int mi = 0; mi < 4; ++mi)
        #pragma unroll
        for (int rr = 0; rr < 4; ++rr)
          stbf(ar, 1024, mi*16 + lg*4 + rr, gn*16 + l15, gelu_f(acc[mi][rr] + b1v));
    }
  }
  __syncthreads();

  { // GEMM2 + bias + residual -> out
    f32x4 acc2[2][4] = {{{0,0,0,0},{0,0,0,0},{0,0,0,0},{0,0,0,0}},
                        {{0,0,0,0},{0,0,0,0},{0,0,0,0},{0,0,0,0}}};
    for (int ks = 0; ks < 16; ++ks) {
      bf16x8 aa[4];
      #pragma unroll
      for (int mi = 0; mi < 4; ++mi) aa[mi] = ldfrag(ar, 1024, l15 + mi*16, ks*32 + lg*8);
      #pragma unroll
      for (int g = 0; g < 2; ++g) {
        int gn = wave*2 + g;
        bf16x8 bf = *reinterpret_cast<const bf16x8*>(w2_f + (size_t)(gn*16 + ks)*512 + lane*8);
        #pragma unroll
        for (int mi = 0; mi < 4; ++mi)
          acc2[g][mi] = __builtin_amdgcn_mfma_f32_16x16x32_bf16(aa[mi], bf, acc2[g][mi], 0, 0, 0);
      }
    }
    #pragma unroll
    for (int g = 0; g < 2; ++g) {
      int col = (wave*2 + g)*16 + l15;
      float b2v = b2[col];
      #pragma unroll
      for (int mi = 0; mi < 4; ++mi)
        #pragma unroll
        for (int rr = 0; rr < 4; ++rr) {
          int tok = mi*16 + lg*4 + rr;
          size_t base = (size_t)(tb + tok)*C_ + col;
          float res;
          if constexpr (sizeof(YT) == 4) res = ((const float*)y)[base];
          else res = bf2f(((const ushort_t*)y)[base]);
          out[base] = res + acc2[g][mi][rr] + b2v;
        }
    }
  }
}

extern "C" void kernel_launch(void* const* d_in, const int* in_sizes, int n_in,
                              void* d_out, int out_size, void* d_ws, size_t ws_size,
                              hipStream_t stream) {
  const float* x    = (const float*)d_in[0];
  const float* g1   = (const float*)d_in[1];
  const float* be1  = (const float*)d_in[2];
  const float* qkvw = (const float*)d_in[3];
  const float* qkvb = (const float*)d_in[4];
  const float* pw   = (const float*)d_in[5];
  const float* pb   = (const float*)d_in[6];
  const float* rpb  = (const float*)d_in[7];
  const float* g2   = (const float*)d_in[8];
  const float* be2  = (const float*)d_in[9];
  const float* w1   = (const float*)d_in[10];
  const float* b1   = (const float*)d_in[11];
  const float* w2   = (const float*)d_in[12];
  const float* b2   = (const float*)d_in[13];
  float* out = (float*)d_out;
  char* ws = (char*)d_ws;

  const size_t nElem = (size_t)4 * H_ * W_ * C_;
  prep_k<<<832, 256, 0, stream>>>(qkvw, pw, w1, w2, rpb, ws);

  if (ws_size >= WSO_Y + nElem*sizeof(float)) {
    float* yv = (float*)(ws + WSO_Y);
    swin_attn_k<float><<<4096, 256, 0, stream>>>(x, g1, be1, qkvb, pb, ws, yv);
    swin_mlp_k<float><<<4096, 256, 0, stream>>>(yv, g2, be2, b1, b2, ws, out);
  } else {
    ushort_t* yv = (ushort_t*)(ws + WSO_Y);
    swin_attn_k<ushort_t><<<4096, 256, 0, stream>>>(x, g1, be1, qkvb, pb, ws, yv);
    swin_mlp_k<ushort_t><<<4096, 256, 0, stream>>>(yv, g2, be2, b1, b2, ws, out);
  }
}

// Round 4
// 553.360 us; speedup vs baseline: 36.1567x; 1.1079x over previous
//
#include <hip/hip_runtime.h>
#include <stdint.h>

typedef unsigned short ushort_t;
typedef __bf16 bf16_t;
typedef bf16_t bf16x8 __attribute__((ext_vector_type(8)));
typedef float f32x4 __attribute__((ext_vector_type(4)));

#define H_ 256
#define W_ 256
#define C_ 128
#define EPSV 1.001e-05f
#define QSCALE 0.17677669529663687f

// d_ws layout (bytes)
#define WSO_QKVW 0u         // ushort[24*4*512]  = 98304 B
#define WSO_PROJW 98304u    // ushort[8*4*512]   = 32768 B
#define WSO_W1   131072u    // ushort[32*4*512]  = 131072 B
#define WSO_W2   262144u    // ushort[8*16*512]  = 131072 B
#define WSO_BIAS 393216u    // bf16 [4][64][64]  = 32768 B

__device__ __forceinline__ ushort_t f2bf(float f) {
  unsigned int u = __float_as_uint(f);
  u += 0x7fffu + ((u >> 16) & 1u);   // RNE
  return (ushort_t)(u >> 16);
}
__device__ __forceinline__ float bf2f(ushort_t u) {
  return __uint_as_float(((unsigned int)u) << 16);
}
__device__ __forceinline__ unsigned int pk2(float a, float b) {
  return (unsigned)f2bf(a) | ((unsigned)f2bf(b) << 16);
}
// bf16 LDS tile access, XOR-swizzled (row stride rowB bytes)
__device__ __forceinline__ bf16x8 ldfrag(const char* base, int rowB, int row, int col) {
  int off = row * rowB + ((col * 2) ^ ((row & 7) << 4));
  return *reinterpret_cast<const bf16x8*>(base + off);
}
__device__ __forceinline__ void stbf(char* base, int rowB, int row, int col, float v) {
  int off = row * rowB + ((col * 2) ^ ((row & 7) << 4));
  *reinterpret_cast<ushort_t*>(base + off) = f2bf(v);
}
// f32 LDS [64][128] tile, rowB=512, swizzled
__device__ __forceinline__ void stf32(char* base, int row, int col, float v) {
  int off = row * 512 + ((col * 4) ^ ((row & 7) << 4));
  *reinterpret_cast<float*>(base + off) = v;
}
__device__ __forceinline__ float ldf32(const char* base, int row, int col) {
  int off = row * 512 + ((col * 4) ^ ((row & 7) << 4));
  return *reinterpret_cast<const float*>(base + off);
}
// fast GELU (tanh form): max abs err vs exact-erf gelu ~3e-3
__device__ __forceinline__ float gelu_f(float v) {
  float u = v * v;
  float z = v * fmaf(0.0713548162726f, u, 1.59576912161f);  // 2*0.7978845608*(v+0.044715 v^3)
  float e = __expf(z);
  float r = __builtin_amdgcn_rcpf(e + 1.0f);
  return v - v * r;                                          // v*(1-r) == 0.5v(1+tanh)
}

// ---------------- prep: weights -> bf16 fragment-major, bias table ----------------
__global__ __launch_bounds__(256)
void prep_k(const float* __restrict__ qkvw, const float* __restrict__ projw,
            const float* __restrict__ w1, const float* __restrict__ w2,
            const float* __restrict__ rpb, char* __restrict__ ws)
{
  int idx = blockIdx.x * 256 + threadIdx.x;   // grid 832 -> 212992 exact
  if (idx < 49152) {                          // qkvw frags: 24 ntiles x 4 ks
    int t = idx >> 9, r = idx & 511; int l = r >> 3, j = r & 7;
    int gn = t >> 2, ks = t & 3;
    int k = ks*32 + (l>>4)*8 + j, n = gn*16 + (l&15);
    ((ushort_t*)(ws + WSO_QKVW))[idx] = f2bf(qkvw[k*384 + n]);
  } else if (idx < 65536) {                   // projw: 8 x 4
    int i = idx - 49152;
    int t = i >> 9, r = i & 511; int l = r >> 3, j = r & 7;
    int gn = t >> 2, ks = t & 3;
    int k = ks*32 + (l>>4)*8 + j, n = gn*16 + (l&15);
    ((ushort_t*)(ws + WSO_PROJW))[i] = f2bf(projw[k*128 + n]);
  } else if (idx < 131072) {                  // w1: 32 x 4
    int i = idx - 65536;
    int t = i >> 9, r = i & 511; int l = r >> 3, j = r & 7;
    int gn = t >> 2, ks = t & 3;
    int k = ks*32 + (l>>4)*8 + j, n = gn*16 + (l&15);
    ((ushort_t*)(ws + WSO_W1))[i] = f2bf(w1[k*512 + n]);
  } else if (idx < 196608) {                  // w2: 8 ntiles x 16 ks
    int i = idx - 131072;
    int t = i >> 9, r = i & 511; int l = r >> 3, j = r & 7;
    int gn = t >> 4, ks = t & 15;
    int k = ks*32 + (l>>4)*8 + j, n = gn*16 + (l&15);
    ((ushort_t*)(ws + WSO_W2))[i] = f2bf(w2[k*128 + n]);
  } else {                                    // bias table bf16 [4][64][64]
    int i = idx - 196608;
    int h = i >> 12, ij = i & 4095, ti = ij >> 6, tj = ij & 63;
    int rel = ((ti>>3) - (tj>>3) + 7)*15 + ((ti&7) - (tj&7) + 7);
    ((ushort_t*)(ws + WSO_BIAS))[i] = f2bf(rpb[rel*4 + h]);
  }
}

// ---------------- fused: LN1 + attn + proj + LN2 + MLP, one block per window ----------------
__global__ __launch_bounds__(256, 2)
void swin_blk_k(const float* __restrict__ x,
                const float* __restrict__ g1, const float* __restrict__ be1,
                const float* __restrict__ qkvb, const float* __restrict__ projb,
                const float* __restrict__ g2, const float* __restrict__ be2,
                const float* __restrict__ b1, const float* __restrict__ b2,
                const char* __restrict__ ws, float* __restrict__ out)
{
  // region time-share:
  // [0,16K):  xw -> ob -> hsm          (bf16 [64][128] swz, rowB 256)
  // [16,32K): qr -> P(w0,w1) -> yst.lo
  // [32,48K): kr -> P(w2,w3) -> yst.hi (yst = f32 [64][128] swz at [16,48K))
  // [48,64K): vT -> a_chunk
  __shared__ __align__(16) char smem[65536];
  __shared__ int rowoff[64];
  __shared__ int lab[64];
  char* xw  = smem;
  char* qr  = smem + 16384;
  char* kr  = smem + 32768;
  char* vT  = smem + 49152;
  char* yst = smem + 16384;
  char* ar  = smem + 49152;

  const ushort_t* qkvw_f  = (const ushort_t*)(ws + WSO_QKVW);
  const ushort_t* projw_f = (const ushort_t*)(ws + WSO_PROJW);
  const ushort_t* w1_f    = (const ushort_t*)(ws + WSO_W1);
  const ushort_t* w2_f    = (const ushort_t*)(ws + WSO_W2);
  const ushort_t* biasT   = (const ushort_t*)(ws + WSO_BIAS);

  const int tid = threadIdx.x, lane = tid & 63, wave = tid >> 6;
  const int l15 = lane & 15, lg = lane >> 4;
  const int blk = blockIdx.x;
  const int b = blk >> 10, w = blk & 1023;
  const int wh = w >> 5, ww = w & 31;

  if (tid < 64) {
    int th = tid >> 3, tw = tid & 7;
    int shh = wh*8 + th, shw = ww*8 + tw;
    int oh = (shh + 4) & (H_-1), ow = (shw + 4) & (W_-1);
    rowoff[tid] = ((b*H_ + oh)*W_ + ow) * C_;
    int hb = (shh < H_-8) ? 0 : ((shh < H_-4) ? 1 : 2);
    int wb = (shw < W_-8) ? 0 : ((shw < W_-4) ? 1 : 2);
    lab[tid] = hb*3 + wb;
  }

  { // ---- Phase 1: LN1 (thread-per-token-quarter) -> xw ----
    int t = tid >> 2, p = tid & 3;
    int th = t >> 3, tw = t & 7;
    int oh = (wh*8 + th + 4) & (H_-1), ow = (ww*8 + tw + 4) & (W_-1);
    const float* xr = x + ((b*H_ + oh)*W_ + ow)*C_ + p*32;
    float xv[32];
    #pragma unroll
    for (int c = 0; c < 8; ++c) *reinterpret_cast<float4*>(xv + c*4) = reinterpret_cast<const float4*>(xr)[c];
    float s = 0.f, s2 = 0.f;
    #pragma unroll
    for (int c = 0; c < 32; ++c) { s += xv[c]; s2 += xv[c]*xv[c]; }
    s += __shfl_xor(s, 1);  s += __shfl_xor(s, 2);
    s2 += __shfl_xor(s2, 1); s2 += __shfl_xor(s2, 2);
    float mean = s*(1.f/128.f), var = s2*(1.f/128.f) - mean*mean;
    float rs = rsqrtf(var + EPSV);
    #pragma unroll
    for (int c8 = 0; c8 < 4; ++c8) {
      uint4 pkv;
      float gv[8], bv[8];
      *reinterpret_cast<float4*>(gv)   = reinterpret_cast<const float4*>(g1  + p*32 + c8*8)[0];
      *reinterpret_cast<float4*>(gv+4) = reinterpret_cast<const float4*>(g1  + p*32 + c8*8)[1];
      *reinterpret_cast<float4*>(bv)   = reinterpret_cast<const float4*>(be1 + p*32 + c8*8)[0];
      *reinterpret_cast<float4*>(bv+4) = reinterpret_cast<const float4*>(be1 + p*32 + c8*8)[1];
      float nv[8];
      #pragma unroll
      for (int j = 0; j < 8; ++j) nv[j] = (xv[c8*8+j] - mean)*rs*gv[j] + bv[j];
      pkv.x = pk2(nv[0],nv[1]); pkv.y = pk2(nv[2],nv[3]);
      pkv.z = pk2(nv[4],nv[5]); pkv.w = pk2(nv[6],nv[7]);
      int off = t*256 + ((p*64 + c8*16) ^ ((t&7) << 4));
      *reinterpret_cast<uint4*>(xw + off) = pkv;
    }
  }
  __syncthreads();   // B1

  { // ---- Phase 2: QKV GEMM (N-split: 6 n-tiles per wave) ----
    bf16x8 afr[4][4];
    #pragma unroll
    for (int mi = 0; mi < 4; ++mi)
      #pragma unroll
      for (int ks = 0; ks < 4; ++ks)
        afr[mi][ks] = ldfrag(xw, 256, l15 + mi*16, ks*32 + lg*8);
    for (int nt = 0; nt < 6; ++nt) {
      int gn = wave*6 + nt;
      f32x4 acc[4] = {{0,0,0,0},{0,0,0,0},{0,0,0,0},{0,0,0,0}};
      #pragma unroll
      for (int ks = 0; ks < 4; ++ks) {
        bf16x8 bf = *reinterpret_cast<const bf16x8*>(qkvw_f + (size_t)(gn*4 + ks)*512 + lane*8);
        #pragma unroll
        for (int mi = 0; mi < 4; ++mi)
          acc[mi] = __builtin_amdgcn_mfma_f32_16x16x32_bf16(afr[mi][ks], bf, acc[mi], 0, 0, 0);
      }
      float bv = qkvb[gn*16 + l15];
      if (gn < 8) {
        #pragma unroll
        for (int mi = 0; mi < 4; ++mi)
          #pragma unroll
          for (int rr = 0; rr < 4; ++rr)
            stbf(qr, 256, mi*16 + lg*4 + rr, gn*16 + l15, (acc[mi][rr] + bv)*QSCALE);
      } else if (gn < 16) {
        #pragma unroll
        for (int mi = 0; mi < 4; ++mi)
          #pragma unroll
          for (int rr = 0; rr < 4; ++rr)
            stbf(kr, 256, mi*16 + lg*4 + rr, (gn-8)*16 + l15, acc[mi][rr] + bv);
      } else {
        #pragma unroll
        for (int mi = 0; mi < 4; ++mi)
          #pragma unroll
          for (int rr = 0; rr < 4; ++rr)
            stbf(vT, 128, (gn-16)*16 + l15, mi*16 + lg*4 + rr, acc[mi][rr] + bv);
      }
    }
  }
  __syncthreads();   // B2

  { // ---- Phase 3: per-head attention (head = wave) ----
    const int h = wave;
    const int ih = 0; (void)ih;
    bf16x8 qa[4], kb[4];
    #pragma unroll
    for (int mi = 0; mi < 4; ++mi) qa[mi] = ldfrag(qr, 256, l15 + mi*16, h*32 + lg*8);
    #pragma unroll
    for (int ni = 0; ni < 4; ++ni) kb[ni] = ldfrag(kr, 256, l15 + ni*16, h*32 + lg*8);
    f32x4 S[4][4];
    #pragma unroll
    for (int mi = 0; mi < 4; ++mi)
      #pragma unroll
      for (int ni = 0; ni < 4; ++ni) {
        f32x4 z = {0,0,0,0};
        S[mi][ni] = __builtin_amdgcn_mfma_f32_16x16x32_bf16(qa[mi], kb[ni], z, 0, 0, 0);
      }
    int labC[4];
    #pragma unroll
    for (int ni = 0; ni < 4; ++ni) labC[ni] = lab[ni*16 + l15];
    float rinv[4][4];
    #pragma unroll
    for (int mi = 0; mi < 4; ++mi)
      #pragma unroll
      for (int rr = 0; rr < 4; ++rr) {
        int row = mi*16 + lg*4 + rr;
        int labR = lab[row];
        const ushort_t* bp = biasT + h*4096 + row*64 + l15;
        #pragma unroll
        for (int ni = 0; ni < 4; ++ni)
          S[mi][ni][rr] += bf2f(bp[ni*16]) + ((labC[ni] == labR) ? 0.f : -100.f);
        float mx = fmaxf(fmaxf(S[mi][0][rr], S[mi][1][rr]), fmaxf(S[mi][2][rr], S[mi][3][rr]));
        mx = fmaxf(mx, __shfl_xor(mx, 1)); mx = fmaxf(mx, __shfl_xor(mx, 2));
        mx = fmaxf(mx, __shfl_xor(mx, 4)); mx = fmaxf(mx, __shfl_xor(mx, 8));
        float sum = 0.f;
        #pragma unroll
        for (int ni = 0; ni < 4; ++ni) {
          float e = __expf(S[mi][ni][rr] - mx);
          S[mi][ni][rr] = e; sum += e;
        }
        sum += __shfl_xor(sum, 1); sum += __shfl_xor(sum, 2);
        sum += __shfl_xor(sum, 4); sum += __shfl_xor(sum, 8);
        rinv[mi][rr] = __builtin_amdgcn_rcpf(sum);
      }
    __syncthreads();   // B3: all waves done reading q/k -> P may overwrite
    char* Pw = smem + 16384 + wave*8192;   // per-wave [64][64] bf16 swz
    #pragma unroll
    for (int mi = 0; mi < 4; ++mi)
      #pragma unroll
      for (int ni = 0; ni < 4; ++ni)
        #pragma unroll
        for (int rr = 0; rr < 4; ++rr)
          stbf(Pw, 128, mi*16 + lg*4 + rr, ni*16 + l15, S[mi][ni][rr]);
    // PV
    f32x4 O[4][2] = {{{0,0,0,0},{0,0,0,0}},{{0,0,0,0},{0,0,0,0}},
                     {{0,0,0,0},{0,0,0,0}},{{0,0,0,0},{0,0,0,0}}};
    #pragma unroll
    for (int ks = 0; ks < 2; ++ks) {
      bf16x8 pa[4];
      #pragma unroll
      for (int mi = 0; mi < 4; ++mi) pa[mi] = ldfrag(Pw, 128, l15 + mi*16, ks*32 + lg*8);
      #pragma unroll
      for (int ni = 0; ni < 2; ++ni) {
        bf16x8 vb = ldfrag(vT, 128, h*32 + ni*16 + l15, ks*32 + lg*8);
        #pragma unroll
        for (int mi = 0; mi < 4; ++mi)
          O[mi][ni] = __builtin_amdgcn_mfma_f32_16x16x32_bf16(pa[mi], vb, O[mi][ni], 0, 0, 0);
      }
    }
    #pragma unroll
    for (int mi = 0; mi < 4; ++mi)
      #pragma unroll
      for (int ni = 0; ni < 2; ++ni)
        #pragma unroll
        for (int rr = 0; rr < 4; ++rr)
          stbf(xw, 256, mi*16 + lg*4 + rr, h*32 + ni*16 + l15, O[mi][ni][rr]*rinv[mi][rr]);
  }
  __syncthreads();   // B4

  { // ---- Phase 4: proj + x-residual -> yst (f32 LDS) ----
    bf16x8 oa[4][4];
    #pragma unroll
    for (int mi = 0; mi < 4; ++mi)
      #pragma unroll
      for (int ks = 0; ks < 4; ++ks)
        oa[mi][ks] = ldfrag(xw, 256, l15 + mi*16, ks*32 + lg*8);
    #pragma unroll
    for (int g = 0; g < 2; ++g) {
      int gn = wave*2 + g;
      f32x4 acc[4] = {{0,0,0,0},{0,0,0,0},{0,0,0,0},{0,0,0,0}};
      #pragma unroll
      for (int ks = 0; ks < 4; ++ks) {
        bf16x8 bf = *reinterpret_cast<const bf16x8*>(projw_f + (size_t)(gn*4 + ks)*512 + lane*8);
        #pragma unroll
        for (int mi = 0; mi < 4; ++mi)
          acc[mi] = __builtin_amdgcn_mfma_f32_16x16x32_bf16(oa[mi][ks], bf, acc[mi], 0, 0, 0);
      }
      float pbv = projb[gn*16 + l15];
      #pragma unroll
      for (int mi = 0; mi < 4; ++mi)
        #pragma unroll
        for (int rr = 0; rr < 4; ++rr) {
          int tok = mi*16 + lg*4 + rr;
          int col = gn*16 + l15;
          float v = acc[mi][rr] + pbv + x[rowoff[tok] + col];
          stf32(yst, tok, col, v);
        }
    }
  }
  __syncthreads();   // B5

  { // ---- Phase 5: LN2 (from yst) -> hsm ----
    int t = tid >> 2, p = tid & 3;
    float xv[32];
    #pragma unroll
    for (int c = 0; c < 8; ++c) {
      int off = t*512 + ((p*128 + c*16) ^ ((t&7) << 4));
      *reinterpret_cast<float4*>(xv + c*4) = *reinterpret_cast<const float4*>(yst + off);
    }
    float s = 0.f, s2 = 0.f;
    #pragma unroll
    for (int c = 0; c < 32; ++c) { s += xv[c]; s2 += xv[c]*xv[c]; }
    s += __shfl_xor(s, 1);  s += __shfl_xor(s, 2);
    s2 += __shfl_xor(s2, 1); s2 += __shfl_xor(s2, 2);
    float mean = s*(1.f/128.f), var = s2*(1.f/128.f) - mean*mean;
    float rs = rsqrtf(var + EPSV);
    #pragma unroll
    for (int c8 = 0; c8 < 4; ++c8) {
      float gv[8], bv[8];
      *reinterpret_cast<float4*>(gv)   = reinterpret_cast<const float4*>(g2  + p*32 + c8*8)[0];
      *reinterpret_cast<float4*>(gv+4) = reinterpret_cast<const float4*>(g2  + p*32 + c8*8)[1];
      *reinterpret_cast<float4*>(bv)   = reinterpret_cast<const float4*>(be2 + p*32 + c8*8)[0];
      *reinterpret_cast<float4*>(bv+4) = reinterpret_cast<const float4*>(be2 + p*32 + c8*8)[1];
      float nv[8];
      #pragma unroll
      for (int j = 0; j < 8; ++j) nv[j] = (xv[c8*8+j] - mean)*rs*gv[j] + bv[j];
      uint4 pkv;
      pkv.x = pk2(nv[0],nv[1]); pkv.y = pk2(nv[2],nv[3]);
      pkv.z = pk2(nv[4],nv[5]); pkv.w = pk2(nv[6],nv[7]);
      int off = t*256 + ((p*64 + c8*16) ^ ((t&7) << 4));
      *reinterpret_cast<uint4*>(smem + off) = pkv;   // hsm = [0,16K)
    }
  }
  __syncthreads();   // B6

  { // ---- Phase 6: MLP, chunked over hidden dim ----
    char* hsm = smem;
    bf16x8 hfr[4][4];
    #pragma unroll
    for (int mi = 0; mi < 4; ++mi)
      #pragma unroll
      for (int ks = 0; ks < 4; ++ks)
        hfr[mi][ks] = ldfrag(hsm, 256, l15 + mi*16, ks*32 + lg*8);
    f32x4 acc2[2][4] = {{{0,0,0,0},{0,0,0,0},{0,0,0,0},{0,0,0,0}},
                        {{0,0,0,0},{0,0,0,0},{0,0,0,0},{0,0,0,0}}};
    for (int cc = 0; cc < 4; ++cc) {
      // GEMM1 chunk: this wave computes 2 n-tiles (regs only, no LDS-a access yet)
      f32x4 a1[2][4];
      #pragma unroll
      for (int gg = 0; gg < 2; ++gg) {
        int gn = cc*8 + wave*2 + gg;
        #pragma unroll
        for (int mi = 0; mi < 4; ++mi) a1[gg][mi] = f32x4{0,0,0,0};
        #pragma unroll
        for (int ks = 0; ks < 4; ++ks) {
          bf16x8 bf = *reinterpret_cast<const bf16x8*>(w1_f + (size_t)(gn*4 + ks)*512 + lane*8);
          #pragma unroll
          for (int mi = 0; mi < 4; ++mi)
            a1[gg][mi] = __builtin_amdgcn_mfma_f32_16x16x32_bf16(hfr[mi][ks], bf, a1[gg][mi], 0, 0, 0);
        }
      }
      __syncthreads();   // previous chunk's GEMM2 readers done (cc=0: PV's vT reads long done)
      #pragma unroll
      for (int gg = 0; gg < 2; ++gg) {
        int gn = cc*8 + wave*2 + gg;
        float b1v = b1[gn*16 + l15];
        #pragma unroll
        for (int mi = 0; mi < 4; ++mi)
          #pragma unroll
          for (int rr = 0; rr < 4; ++rr)
            stbf(ar, 256, mi*16 + lg*4 + rr, (wave*2+gg)*16 + l15, gelu_f(a1[gg][mi][rr] + b1v));
      }
      __syncthreads();   // a_chunk ready
      // GEMM2 partial: K = this chunk's 128 hidden dims
      #pragma unroll
      for (int ks2 = 0; ks2 < 4; ++ks2) {
        bf16x8 aa[4];
        #pragma unroll
        for (int mi = 0; mi < 4; ++mi) aa[mi] = ldfrag(ar, 256, l15 + mi*16, ks2*32 + lg*8);
        #pragma unroll
        for (int g = 0; g < 2; ++g) {
          int gn2 = wave*2 + g;
          bf16x8 bf = *reinterpret_cast<const bf16x8*>(w2_f + (size_t)(gn2*16 + cc*4 + ks2)*512 + lane*8);
          #pragma unroll
          for (int mi = 0; mi < 4; ++mi)
            acc2[g][mi] = __builtin_amdgcn_mfma_f32_16x16x32_bf16(aa[mi], bf, acc2[g][mi], 0, 0, 0);
        }
      }
    }
    // epilogue: out = yst + mlp + b2
    #pragma unroll
    for (int g = 0; g < 2; ++g) {
      int gn2 = wave*2 + g;
      int col = gn2*16 + l15;
      float b2v = b2[col];
      #pragma unroll
      for (int mi = 0; mi < 4; ++mi)
        #pragma unroll
        for (int rr = 0; rr < 4; ++rr) {
          int tok = mi*16 + lg*4 + rr;
          int ro = rowoff[tok] + col;
          out[ro] = ldf32(yst, tok, col) + acc2[g][mi][rr] + b2v;
        }
    }
  }
}

extern "C" void kernel_launch(void* const* d_in, const int* in_sizes, int n_in,
                              void* d_out, int out_size, void* d_ws, size_t ws_size,
                              hipStream_t stream) {
  const float* x    = (const float*)d_in[0];
  const float* g1   = (const float*)d_in[1];
  const float* be1  = (const float*)d_in[2];
  const float* qkvw = (const float*)d_in[3];
  const float* qkvb = (const float*)d_in[4];
  const float* pw   = (const float*)d_in[5];
  const float* pb   = (const float*)d_in[6];
  const float* rpb  = (const float*)d_in[7];
  const float* g2   = (const float*)d_in[8];
  const float* be2  = (const float*)d_in[9];
  const float* w1   = (const float*)d_in[10];
  const float* b1   = (const float*)d_in[11];
  const float* w2   = (const float*)d_in[12];
  const float* b2   = (const float*)d_in[13];
  float* out = (float*)d_out;
  char* ws = (char*)d_ws;

  prep_k<<<832, 256, 0, stream>>>(qkvw, pw, w1, w2, rpb, ws);
  swin_blk_k<<<4096, 256, 0, stream>>>(x, g1, be1, qkvb, pb, g2, be2, b1, b2, ws, out);
}